// Round 2
// baseline (75.204 us; speedup 1.0000x reference)
//
#include <hip/hip_runtime.h>
#include <math.h>

// Problem constants (match reference)
#define B_ 32
#define T_ 8192
#define C_ 64
#define S_ 128           // t-chunks per batch row
#define L_ (T_ / S_)     // 64 t per chunk  (== wave width, one ballot word)
#define EPS_ 1e-8f
#define SIGMA_MIN_ 1e-4f

// Workspace layout (float offsets)
#define SUM_OFF 0                        // B_*S_*C_ = 262144
#define SQ_OFF  262144                   // 262144
#define MS_OFF  524288                   // 262144
#define GAP_OFF 786432                   // B_*S_*4 ints = 16384
#define MU_OFF  802816                   // B_*C_ = 2048
#define INV_OFF 804864                   // 2048
// total = 806912 floats ~= 3.1 MiB

__device__ inline float4 f4add(float4 a, float4 b) {
    return make_float4(a.x + b.x, a.y + b.y, a.z + b.z, a.w + b.w);
}
__device__ inline float4 f4shfl_xor(float4 v, int m) {
    float4 r;
    r.x = __shfl_xor(v.x, m);
    r.y = __shfl_xor(v.y, m);
    r.z = __shfl_xor(v.z, m);
    r.w = __shfl_xor(v.w, m);
    return r;
}

// ---------------- Kernel 1: per-(b,chunk) partial stats + gap tuple ----------
__global__ __launch_bounds__(256) void k1_stats(const float* __restrict__ x,
                                                const float* __restrict__ mask,
                                                float* __restrict__ ws) {
    const int bid = blockIdx.x;            // 0 .. B_*S_-1 (4096)
    const int b   = bid >> 7;              // /S_
    const int s   = bid & (S_ - 1);
    const int tid = threadIdx.x;
    const int cq  = tid & 15;              // channel quad 0..15
    const int row = (tid >> 4) & 3;        // row group within wave
    const int wv  = tid >> 6;              // wave 0..3

    const float4* x4 = (const float4*)x;
    const float4* m4 = (const float4*)mask;
    // float4 index of (b, t, cq*4)
    const long base = ((long)b * T_ + (long)s * L_) * 16 + cq;

    // issue all 8 loads up front (stay in registers, static indexing)
    float4 xv[4], mv[4];
#pragma unroll
    for (int it = 0; it < 4; ++it) {
        long idx = base + (long)(it * 16 + wv * 4 + row) * 16;
        xv[it] = x4[idx];
        mv[it] = m4[idx];
    }

    float4 s1 = make_float4(0.f, 0.f, 0.f, 0.f);
    float4 s2 = make_float4(0.f, 0.f, 0.f, 0.f);
    float4 sm = make_float4(0.f, 0.f, 0.f, 0.f);
#pragma unroll
    for (int it = 0; it < 4; ++it) {
        s1.x += xv[it].x; s1.y += xv[it].y; s1.z += xv[it].z; s1.w += xv[it].w;
        s2.x += xv[it].x * xv[it].x; s2.y += xv[it].y * xv[it].y;
        s2.z += xv[it].z * xv[it].z; s2.w += xv[it].w * xv[it].w;
        sm.x += mv[it].x; sm.y += mv[it].y; sm.z += mv[it].z; sm.w += mv[it].w;
    }

    // reduce across the 4 row-groups of this wave (lane bits 4..5)
    s1 = f4add(s1, f4shfl_xor(s1, 16)); s1 = f4add(s1, f4shfl_xor(s1, 32));
    s2 = f4add(s2, f4shfl_xor(s2, 16)); s2 = f4add(s2, f4shfl_xor(s2, 32));
    sm = f4add(sm, f4shfl_xor(sm, 16)); sm = f4add(sm, f4shfl_xor(sm, 32));

    __shared__ float4 shA[4][16];
    __shared__ float4 shB[4][16];
    __shared__ float4 shC[4][16];
    if ((tid & 63) < 16) { shA[wv][cq] = s1; shB[wv][cq] = s2; shC[wv][cq] = sm; }
    __syncthreads();

    if (tid < 16) {
        float4 a = f4add(f4add(shA[0][tid], shA[1][tid]), f4add(shA[2][tid], shA[3][tid]));
        float4 c = f4add(f4add(shB[0][tid], shB[1][tid]), f4add(shB[2][tid], shB[3][tid]));
        float4 e = f4add(f4add(shC[0][tid], shC[1][tid]), f4add(shC[2][tid], shC[3][tid]));
        const int o = (bid * C_ + tid * 4) >> 2;
        ((float4*)(ws + SUM_OFF))[o] = a;
        ((float4*)(ws + SQ_OFF ))[o] = c;
        ((float4*)(ws + MS_OFF ))[o] = e;
    }

    // ---- gap tuple: chunk == 64 t == one ballot word (channel 0) ----
    if (tid < 64) {
        const float m0 = mask[((long)b * T_ + (long)s * L_ + tid) * C_];
        unsigned long long bal = __ballot(m0 < 0.5f);   // bit i = t order
        if (tid == 0) {
            int pre, suf, best;
            if (bal == ~0ull) {
                pre = 64; suf = 64; best = 64;
            } else {
                pre = __builtin_ctzll(~bal);          // low-bit run of 1s
                suf = __builtin_clzll(~bal);          // high-bit run of 1s
                unsigned long long tmp = bal; best = 0;
                while (tmp) { tmp &= (tmp << 1); ++best; }
            }
            int* gp = (int*)(ws + GAP_OFF) + bid * 4;
            gp[0] = pre; gp[1] = suf; gp[2] = best;
        }
    }
}

// ---------------- Kernel 2: combine partials -> per-(b,c) mu, 1/sigma --------
__global__ __launch_bounds__(256) void k2_params(const int*   __restrict__ phase_id,
                                                 const float* __restrict__ anchor_mu,
                                                 const float* __restrict__ anchor_ls,
                                                 const float* __restrict__ tau0_raw,
                                                 const float* __restrict__ tau1_raw,
                                                 float* __restrict__ ws) {
    const int b   = blockIdx.x;
    const int tid = threadIdx.x;
    const int c   = tid & 63;
    const int p   = tid >> 6;       // 0..3

    __shared__ float sh_gap;
    __shared__ float sh[3][4][64];

    if (tid == 0) {
        const int* gp = (const int*)(ws + GAP_OFF) + b * S_ * 4;
        int pre = 0, suf = 0, best = 0, len = 0;
        for (int s = 0; s < S_; ++s) {
            int p_i = gp[s * 4], s_i = gp[s * 4 + 1], b_i = gp[s * 4 + 2];
            if (s == 0) { pre = p_i; suf = s_i; best = b_i; len = L_; }
            else {
                int cross = suf + p_i;
                best = max(best, max(b_i, cross));
                pre  = (pre == len) ? len + p_i : pre;
                suf  = (s_i == L_) ? suf + L_ : s_i;
                len += L_;
            }
        }
        sh_gap = (float)best / (float)T_;
    }

    float sum = 0.f, sq = 0.f, ms = 0.f;
    for (int s = p; s < S_; s += 4) {
        int o = (b * S_ + s) * C_ + c;
        sum += ws[SUM_OFF + o];
        sq  += ws[SQ_OFF  + o];
        ms  += ws[MS_OFF  + o];
    }
    sh[0][p][c] = sum; sh[1][p][c] = sq; sh[2][p][c] = ms;
    __syncthreads();

    if (tid < 64) {
        sum = sh[0][0][c] + sh[0][1][c] + sh[0][2][c] + sh[0][3][c];
        sq  = sh[1][0][c] + sh[1][1][c] + sh[1][2][c] + sh[1][3][c];
        ms  = sh[2][0][c] + sh[2][1][c] + sh[2][2][c] + sh[2][3][c];

        const float msc    = fmaxf(ms, EPS_);
        const float mu_obs = sum / msc;
        float var = (sq - 2.f * mu_obs * sum + mu_obs * mu_obs * ms) / msc;
        var = fmaxf(var, 0.f);
        const float sigma_obs = sqrtf(var + EPS_);
        const float coverage  = ms / (float)T_;

        const float t0 = log1pf(expf(tau0_raw[0]));   // softplus
        const float t1 = log1pf(expf(tau1_raw[0]));
        const float w  = coverage / (coverage + t0 + t1 * sh_gap + EPS_);

        const int   pid    = phase_id[b];
        const float mu_ref = anchor_mu[pid * C_ + c];
        const float ls_ref = anchor_ls[pid * C_ + c];

        const float mu = w * mu_obs + (1.f - w) * mu_ref;
        const float ls = w * logf(sigma_obs + EPS_) + (1.f - w) * ls_ref;
        const float sigma = fmaxf(expf(ls), SIGMA_MIN_);

        ws[MU_OFF  + b * C_ + c] = mu;
        ws[INV_OFF + b * C_ + c] = 1.f / sigma;
    }
}

// ---------------- Kernel 3: elementwise normalize ---------------------------
__global__ __launch_bounds__(256) void k3_norm(const float* __restrict__ x,
                                               const float* __restrict__ mask,
                                               const float* __restrict__ token,
                                               const float* __restrict__ ws,
                                               float* __restrict__ out) {
    const int gid = blockIdx.x * 256 + threadIdx.x;   // float4 index
    const float4* x4 = (const float4*)x;
    const float4* m4 = (const float4*)mask;
    const float4* mu4  = (const float4*)(ws + MU_OFF);
    const float4* inv4 = (const float4*)(ws + INV_OFF);
    const float4* tk4  = (const float4*)token;

    const int b = gid >> 17;            // T_*C_/4 = 131072 float4 per b
    const int p = b * 16 + (gid & 15);  // (b, channel-quad)

    float4 xv = x4[gid];
    float4 mv = m4[gid];
    float4 mu = mu4[p];
    float4 iv = inv4[p];
    float4 tk = tk4[gid & 15];

    float4 o;
    o.x = mv.x * ((xv.x - mu.x) * iv.x) + (1.f - mv.x) * tk.x;
    o.y = mv.y * ((xv.y - mu.y) * iv.y) + (1.f - mv.y) * tk.y;
    o.z = mv.z * ((xv.z - mu.z) * iv.z) + (1.f - mv.z) * tk.z;
    o.w = mv.w * ((xv.w - mu.w) * iv.w) + (1.f - mv.w) * tk.w;

    ((float4*)out)[gid] = o;
}

extern "C" void kernel_launch(void* const* d_in, const int* in_sizes, int n_in,
                              void* d_out, int out_size, void* d_ws, size_t ws_size,
                              hipStream_t stream) {
    const float* x    = (const float*)d_in[0];
    const float* mask = (const float*)d_in[1];
    const int*   pid  = (const int*)  d_in[2];
    const float* amu  = (const float*)d_in[3];
    const float* als  = (const float*)d_in[4];
    const float* t0   = (const float*)d_in[5];
    const float* t1   = (const float*)d_in[6];
    const float* tok  = (const float*)d_in[7];
    float* out = (float*)d_out;
    float* ws  = (float*)d_ws;

    k1_stats<<<B_ * S_, 256, 0, stream>>>(x, mask, ws);
    k2_params<<<B_, 256, 0, stream>>>(pid, amu, als, t0, t1, ws);
    const int n4 = B_ * T_ * C_ / 4;          // 4194304 float4s
    k3_norm<<<n4 / 256, 256, 0, stream>>>(x, mask, tok, ws, out);
}

// Round 3
// 62.543 us; speedup vs baseline: 1.2024x; 1.2024x over previous
//
#include <hip/hip_runtime.h>
#include <math.h>

// Problem constants (match reference)
#define B_ 32
#define T_ 8192
#define C_ 64
#define S_ 64            // t-chunks per batch row
#define L_ (T_ / S_)     // 128 t per chunk
#define EPS_ 1e-8f
#define SIGMA_MIN_ 1e-4f

// Workspace layout (float offsets)
#define SUM_OFF 0                        // B_*S_*C_ = 131072
#define SQ_OFF  131072
#define MS_OFF  262144
#define GAP_OFF 393216                   // B_*S_*4 ints = 8192
#define MU_OFF  401408                   // B_*C_ = 2048
#define INV_OFF 403456                   // 2048
// total = 405504 floats ~= 1.6 MiB

__device__ inline float4 f4add(float4 a, float4 b) {
    return make_float4(a.x + b.x, a.y + b.y, a.z + b.z, a.w + b.w);
}
__device__ inline float4 f4shfl_xor(float4 v, int m) {
    float4 r;
    r.x = __shfl_xor(v.x, m);
    r.y = __shfl_xor(v.y, m);
    r.z = __shfl_xor(v.z, m);
    r.w = __shfl_xor(v.w, m);
    return r;
}

// tuple for longest-missing-run merge: (pre, suf, best) over a 64-bit word
__device__ inline void word_tuple(unsigned long long w, int& pre, int& suf, int& best) {
    if (w == ~0ull) { pre = 64; suf = 64; best = 64; return; }
    pre = __builtin_ctzll(~w);
    suf = __builtin_clzll(~w);
    unsigned long long tmp = w; best = 0;
    while (tmp) { tmp &= (tmp << 1); ++best; }
}

// ---------------- Kernel 1: per-(b,chunk) partial stats + gap tuple ----------
__global__ __launch_bounds__(256) void k1_stats(const float* __restrict__ x,
                                                const float* __restrict__ mask,
                                                float* __restrict__ ws) {
    const int bid = blockIdx.x;            // 0 .. B_*S_-1 (2048)
    const int b   = bid >> 6;              // /S_
    const int s   = bid & (S_ - 1);
    const int tid = threadIdx.x;
    const int cq  = tid & 15;              // channel quad 0..15
    const int tr  = tid >> 4;              // t-row 0..15
    const int wv  = tid >> 6;              // wave 0..3

    const float4* x4 = (const float4*)x;
    const float4* m4 = (const float4*)mask;
    // float4 index of (b, t, cq*4); t = s*L_ + it*16 + tr
    const long base = ((long)b * T_ + (long)s * L_ + tr) * 16 + cq;

    // ---- issue ALL 16 loads before any ALU (force MLP) ----
    float4 xa[8], ma[8];
#pragma unroll
    for (int it = 0; it < 8; ++it) xa[it] = x4[base + (long)(it * 16) * 16];
#pragma unroll
    for (int it = 0; it < 8; ++it) ma[it] = m4[base + (long)(it * 16) * 16];
    __builtin_amdgcn_sched_barrier(0);

    float4 s1 = make_float4(0.f, 0.f, 0.f, 0.f);
    float4 s2 = make_float4(0.f, 0.f, 0.f, 0.f);
    float4 sm = make_float4(0.f, 0.f, 0.f, 0.f);
#pragma unroll
    for (int it = 0; it < 8; ++it) {
        s1.x += xa[it].x; s1.y += xa[it].y; s1.z += xa[it].z; s1.w += xa[it].w;
        s2.x += xa[it].x * xa[it].x; s2.y += xa[it].y * xa[it].y;
        s2.z += xa[it].z * xa[it].z; s2.w += xa[it].w * xa[it].w;
        sm.x += ma[it].x; sm.y += ma[it].y; sm.z += ma[it].z; sm.w += ma[it].w;
    }

    __shared__ float4 shA[4][16];
    __shared__ float4 shB[4][16];
    __shared__ float4 shC[4][16];
    __shared__ unsigned char misbyte[L_];

    // channel-0 missing bits from registers (no extra global traffic)
    if (cq == 0) {
#pragma unroll
        for (int it = 0; it < 8; ++it)
            misbyte[it * 16 + tr] = (ma[it].x < 0.5f) ? 1 : 0;
    }

    // reduce across the 4 t-row groups of this wave (lane bits 4..5)
    s1 = f4add(s1, f4shfl_xor(s1, 16)); s1 = f4add(s1, f4shfl_xor(s1, 32));
    s2 = f4add(s2, f4shfl_xor(s2, 16)); s2 = f4add(s2, f4shfl_xor(s2, 32));
    sm = f4add(sm, f4shfl_xor(sm, 16)); sm = f4add(sm, f4shfl_xor(sm, 32));

    if ((tid & 63) < 16) { shA[wv][cq] = s1; shB[wv][cq] = s2; shC[wv][cq] = sm; }
    __syncthreads();

    if (tid < 16) {
        float4 a = f4add(f4add(shA[0][tid], shA[1][tid]), f4add(shA[2][tid], shA[3][tid]));
        float4 c = f4add(f4add(shB[0][tid], shB[1][tid]), f4add(shB[2][tid], shB[3][tid]));
        float4 e = f4add(f4add(shC[0][tid], shC[1][tid]), f4add(shC[2][tid], shC[3][tid]));
        const int o = (bid * C_ + tid * 4) >> 2;
        ((float4*)(ws + SUM_OFF))[o] = a;
        ((float4*)(ws + SQ_OFF ))[o] = c;
        ((float4*)(ws + MS_OFF ))[o] = e;
    }

    // ---- gap tuple for the 128-t chunk: two ballots on wave 0 ----
    if (tid < 64) {
        const int m0 = misbyte[tid];
        const int m1 = misbyte[64 + tid];
        unsigned long long w0 = __ballot(m0 != 0);
        unsigned long long w1 = __ballot(m1 != 0);
        if (tid == 0) {
            int p0, s0, b0, p1, s1i, b1;
            word_tuple(w0, p0, s0, b0);
            word_tuple(w1, p1, s1i, b1);
            int pre  = (p0 == 64) ? 64 + p1 : p0;
            int suf  = (s1i == 64) ? s0 + 64 : s1i;
            int best = max(max(b0, b1), s0 + p1);
            ((int4*)((int*)(ws + GAP_OFF)))[bid] = make_int4(pre, suf, best, L_);
        }
    }
}

// ---------------- Kernel 2: combine partials -> per-(b,c) mu, 1/sigma --------
__global__ __launch_bounds__(256) void k2_params(const int*   __restrict__ phase_id,
                                                 const float* __restrict__ anchor_mu,
                                                 const float* __restrict__ anchor_ls,
                                                 const float* __restrict__ tau0_raw,
                                                 const float* __restrict__ tau1_raw,
                                                 float* __restrict__ ws) {
    const int b   = blockIdx.x;
    const int tid = threadIdx.x;
    const int c   = tid & 63;
    const int p   = tid >> 6;       // 0..3

    __shared__ float sh_gap;
    __shared__ float sh[3][4][64];

    // ---- parallel gap merge on wave 0: 64 tuples, ordered butterfly ----
    if (tid < 64) {
        int4 t4 = ((const int4*)((const int*)(ws + GAP_OFF)))[b * S_ + tid];
        int pre = t4.x, suf = t4.y, best = t4.z, len = t4.w;
#pragma unroll
        for (int m = 1; m < 64; m <<= 1) {
            int ppre = __shfl_xor(pre, m);
            int psuf = __shfl_xor(suf, m);
            int pbest = __shfl_xor(best, m);
            int plen = __shfl_xor(len, m);
            int l_pre, l_suf, l_best, l_len, r_pre, r_suf, r_best, r_len;
            if (tid & m) {   // partner is LEFT
                l_pre = ppre; l_suf = psuf; l_best = pbest; l_len = plen;
                r_pre = pre;  r_suf = suf;  r_best = best;  r_len = len;
            } else {         // partner is RIGHT
                l_pre = pre;  l_suf = suf;  l_best = best;  l_len = len;
                r_pre = ppre; r_suf = psuf; r_best = pbest; r_len = plen;
            }
            best = max(max(l_best, r_best), l_suf + r_pre);
            pre  = (l_pre == l_len) ? l_len + r_pre : l_pre;
            suf  = (r_suf == r_len) ? r_len + l_suf : r_suf;
            len  = l_len + r_len;
        }
        if (tid == 0) sh_gap = (float)best / (float)T_;
    }

    float sum = 0.f, sq = 0.f, ms = 0.f;
    for (int s = p; s < S_; s += 4) {
        int o = (b * S_ + s) * C_ + c;
        sum += ws[SUM_OFF + o];
        sq  += ws[SQ_OFF  + o];
        ms  += ws[MS_OFF  + o];
    }
    sh[0][p][c] = sum; sh[1][p][c] = sq; sh[2][p][c] = ms;
    __syncthreads();

    if (tid < 64) {
        sum = sh[0][0][c] + sh[0][1][c] + sh[0][2][c] + sh[0][3][c];
        sq  = sh[1][0][c] + sh[1][1][c] + sh[1][2][c] + sh[1][3][c];
        ms  = sh[2][0][c] + sh[2][1][c] + sh[2][2][c] + sh[2][3][c];

        const float msc    = fmaxf(ms, EPS_);
        const float mu_obs = sum / msc;
        float var = (sq - 2.f * mu_obs * sum + mu_obs * mu_obs * ms) / msc;
        var = fmaxf(var, 0.f);
        const float sigma_obs = sqrtf(var + EPS_);
        const float coverage  = ms / (float)T_;

        const float t0 = log1pf(expf(tau0_raw[0]));   // softplus
        const float t1 = log1pf(expf(tau1_raw[0]));
        const float w  = coverage / (coverage + t0 + t1 * sh_gap + EPS_);

        const int   pid    = phase_id[b];
        const float mu_ref = anchor_mu[pid * C_ + c];
        const float ls_ref = anchor_ls[pid * C_ + c];

        const float mu = w * mu_obs + (1.f - w) * mu_ref;
        const float ls = w * logf(sigma_obs + EPS_) + (1.f - w) * ls_ref;
        const float sigma = fmaxf(expf(ls), SIGMA_MIN_);

        ws[MU_OFF  + b * C_ + c] = mu;
        ws[INV_OFF + b * C_ + c] = 1.f / sigma;
    }
}

// ---------------- Kernel 3: elementwise normalize ---------------------------
__global__ __launch_bounds__(256) void k3_norm(const float* __restrict__ x,
                                               const float* __restrict__ mask,
                                               const float* __restrict__ token,
                                               const float* __restrict__ ws,
                                               float* __restrict__ out) {
    const int gid = blockIdx.x * 256 + threadIdx.x;   // float4 index
    const float4* x4 = (const float4*)x;
    const float4* m4 = (const float4*)mask;
    const float4* mu4  = (const float4*)(ws + MU_OFF);
    const float4* inv4 = (const float4*)(ws + INV_OFF);
    const float4* tk4  = (const float4*)token;

    const int b = gid >> 17;            // T_*C_/4 = 131072 float4 per b
    const int p = b * 16 + (gid & 15);  // (b, channel-quad)

    float4 xv = x4[gid];
    float4 mv = m4[gid];
    float4 mu = mu4[p];
    float4 iv = inv4[p];
    float4 tk = tk4[gid & 15];

    float4 o;
    o.x = mv.x * ((xv.x - mu.x) * iv.x) + (1.f - mv.x) * tk.x;
    o.y = mv.y * ((xv.y - mu.y) * iv.y) + (1.f - mv.y) * tk.y;
    o.z = mv.z * ((xv.z - mu.z) * iv.z) + (1.f - mv.z) * tk.z;
    o.w = mv.w * ((xv.w - mu.w) * iv.w) + (1.f - mv.w) * tk.w;

    ((float4*)out)[gid] = o;
}

extern "C" void kernel_launch(void* const* d_in, const int* in_sizes, int n_in,
                              void* d_out, int out_size, void* d_ws, size_t ws_size,
                              hipStream_t stream) {
    const float* x    = (const float*)d_in[0];
    const float* mask = (const float*)d_in[1];
    const int*   pid  = (const int*)  d_in[2];
    const float* amu  = (const float*)d_in[3];
    const float* als  = (const float*)d_in[4];
    const float* t0   = (const float*)d_in[5];
    const float* t1   = (const float*)d_in[6];
    const float* tok  = (const float*)d_in[7];
    float* out = (float*)d_out;
    float* ws  = (float*)d_ws;

    k1_stats<<<B_ * S_, 256, 0, stream>>>(x, mask, ws);
    k2_params<<<B_, 256, 0, stream>>>(pid, amu, als, t0, t1, ws);
    const int n4 = B_ * T_ * C_ / 4;          // 4194304 float4s
    k3_norm<<<n4 / 256, 256, 0, stream>>>(x, mask, tok, ws, out);
}